// Round 7
// baseline (260.594 us; speedup 1.0000x reference)
//
#include <hip/hip_runtime.h>
#include <hip/hip_fp16.h>
#include <stdint.h>

// Problem dims (fixed by reference)
// Reference dtypes: x fp16, bias fp16, out fp16 -> harness passes/reads FLOAT32.
// packed_w int32 (8192 x 512), 16 two-bit codes per word, values {0,1,3}.
#define M_DIM 1024
#define N_DIM 8192
#define K_DIM 8192
#define KP    (K_DIM / 16)   // 512 packed int32 words per weight row

#define BM 128
#define BN 64                 // halved vs R6: grid 1024 -> 4 blocks/CU (occupancy lever)
#define BK 64
#define NTHREADS 256
#define A_STRIDE 128          // fp16 A tile row: 64*2 B, unpadded (global_load_lds), XOR-swizzled
#define B_STRIDE 144          // fp16 B tile row: 128 B + 16 pad

typedef _Float16 half8   __attribute__((ext_vector_type(8)));
typedef __fp16   fp16x2  __attribute__((ext_vector_type(2)));
typedef float    f32x4   __attribute__((ext_vector_type(4)));
typedef float    f32x16  __attribute__((ext_vector_type(16)));

#define AS1(p) ((const __attribute__((address_space(1))) void*)(p))
#define AS3(p) ((__attribute__((address_space(3))) void*)(p))

__device__ __forceinline__ uint32_t cvt2(float a, float b) {
  fp16x2 p = __builtin_amdgcn_cvt_pkrtz(a, b);   // RTZ exact: values are fp16-representable
  return __builtin_bit_cast(uint32_t, p);
}

// ---- v_perm ternary decode (R5, verified) ----
// fp16 table bytes T = [0x00, 0x3C, 0x06, 0x42]; low byte of every value is 0x00.
// Spread trick: ((lo2 | hi2<<8) * 0x1001) & 0x03030303 -> sel bytes [c0,c1,c2,c3]
// (cross terms <= 6<<4, never carry across byte lanes).
__device__ __forceinline__ void unpack_word(uint32_t u, uint32_t out[8]) {
  const uint32_t T = 0x42063C00u;
  uint32_t U0 = u & 0x33333333u;
  uint32_t U1 = (u >> 2) & 0x33333333u;
#pragma unroll
  for (int b = 0; b < 4; ++b) {
    uint32_t lo2 = (U0 >> (8 * b)) & 0xFFu;
    uint32_t hi2 = (U1 >> (8 * b)) & 0xFFu;
    uint32_t sel = ((lo2 | (hi2 << 8)) * 0x1001u) & 0x03030303u;
    uint32_t P = __builtin_amdgcn_perm(0u, T, sel);             // [T[c0],T[c1],T[c2],T[c3]]
    out[2 * b]     = __builtin_amdgcn_perm(P, 0u, 0x05000400u); // fp16(c0),fp16(c1)
    out[2 * b + 1] = __builtin_amdgcn_perm(P, 0u, 0x07000600u); // fp16(c2),fp16(c3)
  }
}

// ---- pre-pass: x f32 -> fp16 into workspace (exact) ----
__global__ __launch_bounds__(256)
void cvt_x(const float* __restrict__ x, uint16_t* __restrict__ xh) {
  int i = (blockIdx.x * 256 + threadIdx.x) * 8;
  float4 a = *(const float4*)(x + i);
  float4 b = *(const float4*)(x + i + 4);
  uint4 o;
  o.x = cvt2(a.x, a.y); o.y = cvt2(a.z, a.w);
  o.z = cvt2(b.x, b.y); o.w = cvt2(b.z, b.w);
  *(uint4*)(xh + i) = o;
}

// ========== fast path: 128x64 tile, 32x32x16 MFMA, 4 blocks/CU ==========
__global__ __launch_bounds__(NTHREADS, 4)
void ternary_gemm_ws(const uint16_t* __restrict__ xh,
                     const int*      __restrict__ pw,
                     const float*    __restrict__ bias,
                     float*          __restrict__ out) {
  __shared__ __align__(16) char AsB[BM * A_STRIDE];  // 16 KiB
  __shared__ __align__(16) char BsB[BN * B_STRIDE];  // 9 KiB

  const int tid  = threadIdx.x;
  const int lane = tid & 63;
  const int w    = tid >> 6;
  const int wm   = w >> 1, wn = w & 1;   // wave tile: 64(m) x 32(n)
  const int bid  = blockIdx.x;
  const int bm   = (bid & 7) * BM;    // XCD swizzle: one 2 MiB A-slab per XCD hot in L2
  const int bn   = (bid >> 3) * BN;   // 128 n-tiles

  // A staging (unchanged from R6): instr q covers rows w*32+q*8..+7;
  // lane -> row +(lane>>3), LDS slot lane&7; slot s of row r holds chunk c = s ^ (r&7).
  const int ar = lane >> 3;
  const int ac = (lane & 7) ^ ar;
  const char* gA[4];
  char*       lA[4];
#pragma unroll
  for (int q = 0; q < 4; ++q) {
    int row = w * 32 + q * 8 + ar;
    gA[q] = (const char*)xh + (size_t)(bm + row) * (K_DIM * 2) + ac * 16;
    lA[q] = AsB + w * 4096 + q * 1024;       // wave-uniform base; HW adds lane*16
  }

  // B staging: 64 rows x 4 words per K-tile = 256 words; thread t -> row t>>2, word t&3.
  const int rB = tid >> 2, wB = tid & 3;
  const int* gBw = pw + (size_t)(bn + rB) * KP + wB;
  char* const dB0 = BsB + rB * B_STRIDE + wB * 32;   // chunks 2*wB, 2*wB+1

  // Fragment offsets (kt-invariant), 32x32x16 operand layout (verified R6):
  //   A: lane holds A[m=lane&31][k=(lane>>5)*8+j];  B: W[n=lane&31][k=(lane>>5)*8+j]
  int offA[2][4], offB[4];
#pragma unroll
  for (int ks = 0; ks < 4; ++ks) {
    int c = ks * 2 + (lane >> 5);
#pragma unroll
    for (int i = 0; i < 2; ++i) {
      int rowA = wm * 64 + i * 32 + (lane & 31);
      offA[i][ks] = rowA * A_STRIDE + ((c ^ (rowA & 7)) * 16);
    }
    offB[ks] = (wn * 32 + (lane & 31)) * B_STRIDE + c * 16;
  }

  f32x16 acc[2];
#pragma unroll
  for (int i = 0; i < 2; ++i) acc[i] = (f32x16)(0.f);

  const int NT = K_DIM / BK;   // 128
  uint32_t wcur = *gBw;        // prefetch tile 0's packed word

  for (int kt = 0; kt < NT; ++kt) {
    __syncthreads();           // all waves done reading previous tile's LDS

    // A: async global->LDS (drained by vmcnt(0) at the next barrier)
#pragma unroll
    for (int q = 0; q < 4; ++q) {
      __builtin_amdgcn_global_load_lds(AS1(gA[q]), AS3(lA[q]), 16, 0, 0);
      gA[q] += BK * 2;
    }

    // B: prefetch next tile's word; decode current -> LDS
    const int kn = (kt + 1 < NT) ? (kt + 1) : kt;
    uint32_t wnxt = gBw[kn * 4];
    uint32_t o[8];
    unpack_word(wcur, o);
    *(uint4*)(dB0)      = make_uint4(o[0], o[1], o[2], o[3]);
    *(uint4*)(dB0 + 16) = make_uint4(o[4], o[5], o[6], o[7]);

    __syncthreads();           // staging visible (vmcnt+lgkmcnt drained)

#pragma unroll
    for (int ks = 0; ks < 4; ++ks) {
      half8 af0 = *(const half8*)(AsB + offA[0][ks]);
      half8 af1 = *(const half8*)(AsB + offA[1][ks]);
      half8 bf  = *(const half8*)(BsB + offB[ks]);
      acc[0] = __builtin_amdgcn_mfma_f32_32x32x16_f16(af0, bf, acc[0], 0, 0, 0);
      acc[1] = __builtin_amdgcn_mfma_f32_32x32x16_f16(af1, bf, acc[1], 0, 0, 0);
    }
    wcur = wnxt;
  }

  // Epilogue: 32x32 C/D layout (m74/m101): col(n)=lane&31, row(m)=(reg&3)+8*(reg>>2)+4*(lane>>5)
  // fp16 rounding replicated exactly: f16(y) + f16(bias) in half, widen to f32.
  {
    int n = bn + wn * 32 + (lane & 31);
    __half hb = __float2half_rn(bias[n]);
#pragma unroll
    for (int i = 0; i < 2; ++i) {
      int mbase = bm + wm * 64 + i * 32 + 4 * (lane >> 5);
#pragma unroll
      for (int reg = 0; reg < 16; ++reg) {
        int m = mbase + (reg & 3) + 8 * (reg >> 2);
        __half hy = __float2half_rn(acc[i][reg]);
        out[(size_t)m * N_DIM + n] = __half2float(__hadd(hy, hb));
      }
    }
  }
}

// ================= fallback (R4 kernel, known-good): used only if ws too small =================
__device__ __forceinline__ uint32_t unpack_pair16(uint32_t u, int p) {
  uint32_t c0 = (u >> (4 * p)) & 3u;
  uint32_t c1 = (u >> (4 * p + 2)) & 3u;
  uint32_t lo = (c0 & 1u) * 0x3C00u + (c0 >> 1) * 0x0600u;
  uint32_t hi = (c1 & 1u) * 0x3C00u + (c1 >> 1) * 0x0600u;
  return lo | (hi << 16);
}

__global__ __launch_bounds__(NTHREADS, 2)
void ternary_gemm(const float* __restrict__ x,
                  const int*   __restrict__ pw,
                  const float* __restrict__ bias,
                  float*       __restrict__ out) {
  __shared__ __align__(16) char AsB[128 * B_STRIDE];
  __shared__ __align__(16) char BsB[128 * B_STRIDE];

  const int tid  = threadIdx.x;
  const int lane = tid & 63;
  const int w    = tid >> 6;
  const int wm   = w >> 1, wn = w & 1;
  const int bid  = blockIdx.x;
  const int bm   = (bid & 7) * 128;
  const int bn   = (bid >> 3) * 128;

  const int rT = tid >> 1, hT = tid & 1;
  const float* gA = x + (size_t)(bm + rT) * K_DIM + hT * 32;
  char* const  lA = AsB + rT * B_STRIDE + hT * 64;
  const int2* gB = (const int2*)pw + (size_t)(bn + rT) * (KP / 2) + hT;
  char* dBp[4];
#pragma unroll
  for (int h = 0; h < 4; ++h)
    dBp[h] = BsB + rT * B_STRIDE + (hT * 4 + h) * 16;

  int offA[4][2], offB[4][2];
#pragma unroll
  for (int i = 0; i < 4; ++i)
#pragma unroll
    for (int ks = 0; ks < 2; ++ks) {
      int c = ks * 4 + (lane >> 4);
      offA[i][ks] = (wm * 64 + i * 16 + (lane & 15)) * B_STRIDE + c * 16;
      offB[i][ks] = (wn * 64 + i * 16 + (lane & 15)) * B_STRIDE + c * 16;
    }

  f32x4 acc[4][4];
#pragma unroll
  for (int i = 0; i < 4; ++i)
#pragma unroll
    for (int j = 0; j < 4; ++j)
      acc[i][j] = (f32x4){0.f, 0.f, 0.f, 0.f};

  const int NT = K_DIM / BK;
  for (int kt = 0; kt < NT; ++kt) {
    __syncthreads();
    int2 wcur = gB[kt * 2];
    float4 av[8];
#pragma unroll
    for (int v = 0; v < 8; ++v) av[v] = *(const float4*)(gA + kt * BK + v * 4);
    uint32_t d0[8], d1[8];
#pragma unroll
    for (int p = 0; p < 8; ++p) d0[p] = unpack_pair16((uint32_t)wcur.x, p);
#pragma unroll
    for (int p = 0; p < 8; ++p) d1[p] = unpack_pair16((uint32_t)wcur.y, p);
    *(uint4*)dBp[0] = make_uint4(d0[0], d0[1], d0[2], d0[3]);
    *(uint4*)dBp[1] = make_uint4(d0[4], d0[5], d0[6], d0[7]);
    *(uint4*)dBp[2] = make_uint4(d1[0], d1[1], d1[2], d1[3]);
    *(uint4*)dBp[3] = make_uint4(d1[4], d1[5], d1[6], d1[7]);
#pragma unroll
    for (int v = 0; v < 4; ++v) {
      uint4 aw;
      aw.x = cvt2(av[2 * v].x, av[2 * v].y);
      aw.y = cvt2(av[2 * v].z, av[2 * v].w);
      aw.z = cvt2(av[2 * v + 1].x, av[2 * v + 1].y);
      aw.w = cvt2(av[2 * v + 1].z, av[2 * v + 1].w);
      *(uint4*)(lA + v * 16) = aw;
    }
    __syncthreads();
#pragma unroll
    for (int ks = 0; ks < 2; ++ks) {
      half8 af[4], bf[4];
#pragma unroll
      for (int i = 0; i < 4; ++i) af[i] = *(const half8*)(AsB + offA[i][ks]);
#pragma unroll
      for (int j = 0; j < 4; ++j) bf[j] = *(const half8*)(BsB + offB[j][ks]);
#pragma unroll
      for (int i = 0; i < 4; ++i)
#pragma unroll
        for (int j = 0; j < 4; ++j)
          acc[i][j] = __builtin_amdgcn_mfma_f32_16x16x32_f16(af[i], bf[j], acc[i][j], 0, 0, 0);
    }
  }
#pragma unroll
  for (int j = 0; j < 4; ++j) {
    int n = bn + wn * 64 + j * 16 + (lane & 15);
    __half hb = __float2half_rn(bias[n]);
#pragma unroll
    for (int i = 0; i < 4; ++i) {
      int m0 = bm + wm * 64 + i * 16 + (lane >> 4) * 4;
#pragma unroll
      for (int r = 0; r < 4; ++r) {
        __half hy = __float2half_rn(acc[i][j][r]);
        out[(size_t)(m0 + r) * N_DIM + n] = __half2float(__hadd(hy, hb));
      }
    }
  }
}

extern "C" void kernel_launch(void* const* d_in, const int* in_sizes, int n_in,
                              void* d_out, int out_size, void* d_ws, size_t ws_size,
                              hipStream_t stream) {
  (void)in_sizes; (void)n_in; (void)out_size;
  const float* x    = (const float*)d_in[0];
  const int*   pwp  = (const int*)d_in[1];
  const float* bias = (const float*)d_in[2];
  float*       outp = (float*)d_out;

  const size_t need = (size_t)M_DIM * K_DIM * 2;   // 16 MiB fp16 x
  if (ws_size >= need) {
    uint16_t* xh = (uint16_t*)d_ws;
    cvt_x<<<(M_DIM * K_DIM) / (256 * 8), 256, 0, stream>>>(x, xh);
    dim3 grid((M_DIM / BM) * (N_DIM / BN));        // 8 * 128 = 1024 blocks
    ternary_gemm_ws<<<grid, NTHREADS, 0, stream>>>(xh, pwp, bias, outp);
  } else {
    dim3 grid((M_DIM / 128) * (N_DIM / 128));      // 512 blocks
    ternary_gemm<<<grid, NTHREADS, 0, stream>>>(x, pwp, bias, outp);
  }
}

// Round 8
// 239.258 us; speedup vs baseline: 1.0892x; 1.0892x over previous
//
#include <hip/hip_runtime.h>
#include <hip/hip_fp16.h>
#include <stdint.h>

// Problem dims (fixed by reference)
// Reference dtypes: x fp16, bias fp16, out fp16 -> harness passes/reads FLOAT32.
// packed_w int32 (8192 x 512), 16 two-bit codes per word, values {0,1,3}.
#define M_DIM 1024
#define N_DIM 8192
#define K_DIM 8192
#define KP    (K_DIM / 16)   // 512 packed int32 words per weight row

#define BM 128
#define BN 128
#define BK 64
#define NTHREADS 256
#define B_STRIDE 144          // fp16 B tile row: 128 B + 16 pad
#define B_BUF    (BN * B_STRIDE)   // 18432 B per buffer, x2 double-buffered

// Transposed A workspace layout (bytes), built by cvt_x_t:
//   mt(8):2 MiB | kt(128):16 KiB | i32(4):4 KiB | ks(4):1 KiB | q(2):512 | r(32):16
// A-fragment (i32, ks) = contiguous 1 KB at base + lane*16 (lane = q*32+r).
#define MT_STRIDE 2097152
#define KT_STRIDE 16384

typedef _Float16 half8   __attribute__((ext_vector_type(8)));
typedef __fp16   fp16x2  __attribute__((ext_vector_type(2)));
typedef float    f32x4   __attribute__((ext_vector_type(4)));
typedef float    f32x16  __attribute__((ext_vector_type(16)));

__device__ __forceinline__ uint32_t cvt2(float a, float b) {
  fp16x2 p = __builtin_amdgcn_cvt_pkrtz(a, b);   // RTZ exact: values are fp16-representable
  return __builtin_bit_cast(uint32_t, p);
}

// ---- v_perm ternary decode (R5, verified) ----
__device__ __forceinline__ void unpack_word(uint32_t u, uint32_t out[8]) {
  const uint32_t T = 0x42063C00u;   // bytes [0x00,0x3C,0x06,0x42] = hi-bytes of fp16(0,1,2,3)
  uint32_t U0 = u & 0x33333333u;
  uint32_t U1 = (u >> 2) & 0x33333333u;
#pragma unroll
  for (int b = 0; b < 4; ++b) {
    uint32_t lo2 = (U0 >> (8 * b)) & 0xFFu;
    uint32_t hi2 = (U1 >> (8 * b)) & 0xFFu;
    uint32_t sel = ((lo2 | (hi2 << 8)) * 0x1001u) & 0x03030303u;
    uint32_t P = __builtin_amdgcn_perm(0u, T, sel);
    out[2 * b]     = __builtin_amdgcn_perm(P, 0u, 0x05000400u);
    out[2 * b + 1] = __builtin_amdgcn_perm(P, 0u, 0x07000600u);
  }
}

// ---- pre-pass: x f32 -> fp16, transposed-tiled into workspace ----
// One block per (mt, kt): reads 128 rows x 64 k (32 KB f32), writes 16 KB fp16.
__global__ __launch_bounds__(256)
void cvt_x_t(const float* __restrict__ x, char* __restrict__ xhT) {
  __shared__ __align__(16) char st[16384];
  const int b  = blockIdx.x;
  const int mt = b >> 7, kt = b & 127;
  const int t  = threadIdx.x;
#pragma unroll
  for (int p = 0; p < 8; ++p) {
    int f   = t + 256 * p;     // float4 index in tile [0,2048)
    int R   = f >> 4;          // row in tile (16 float4 per row)
    int cc4 = f & 15;          // float4 within row
    float4 v = *(const float4*)(x + (size_t)(mt * 128 + R) * K_DIM + kt * 64 + cc4 * 4);
    uint32_t w0 = cvt2(v.x, v.y), w1 = cvt2(v.z, v.w);
    int c8 = cc4 >> 1, hh = cc4 & 1;
    int i32 = R >> 5, r = R & 31, ks = c8 >> 1, q = c8 & 1;
    *(uint2*)(st + i32 * 4096 + ks * 1024 + q * 512 + r * 16 + hh * 8) = make_uint2(w0, w1);
  }
  __syncthreads();
  char* outb = xhT + (size_t)mt * MT_STRIDE + (size_t)kt * KT_STRIDE;
#pragma unroll
  for (int e = 0; e < 4; ++e) {
    int d = (e * 256 + t) * 16;      // lane-consecutive: coalesced + conflict-free
    *(uint4*)(outb + d) = *(const uint4*)(st + d);
  }
}

// ========== fast path: A in registers (transposed ws), B dbuf LDS, 1 barrier/tile ==========
__global__ __launch_bounds__(NTHREADS, 2)
void ternary_gemm_rA(const char* __restrict__ xhT,
                     const int*  __restrict__ pw,
                     const float* __restrict__ bias,
                     float*       __restrict__ out) {
  __shared__ __align__(16) char BsB[2 * B_BUF];   // 36 KiB, B only

  const int tid  = threadIdx.x;
  const int lane = tid & 63;
  const int w    = tid >> 6;
  const int wm   = w >> 1, wn = w & 1;
  const int bid  = blockIdx.x;
  const int mt   = bid & 7;           // XCD swizzle: one 2 MiB A-slab per XCD hot in L2
  const int bm   = mt * BM;
  const int bn   = (bid >> 3) * BN;

  // A register-load pointers: i in {0,1} -> i32 = wm*2+i. Fragment (ks) at imm ks*1024.
  const char* pA[2];
#pragma unroll
  for (int i = 0; i < 2; ++i)
    pA[i] = xhT + (size_t)mt * MT_STRIDE + (wm * 2 + i) * 4096 + lane * 16;

  // B staging: thread t -> row t>>1, packed words (t&1)*2..+1 per K-tile
  const int rT = tid >> 1, hT = tid & 1;
  const int2* gB = (const int2*)pw + (size_t)(bn + rT) * (KP / 2) + hT;
  int dBoff[4];
#pragma unroll
  for (int h = 0; h < 4; ++h) dBoff[h] = rT * B_STRIDE + (hT * 4 + h) * 16;

  // B fragment offsets: W[n=lane&31][k=(lane>>5)*8+j], chunk = ks*2 + quad
  int offB[2][4];
#pragma unroll
  for (int j = 0; j < 2; ++j)
#pragma unroll
    for (int ks = 0; ks < 4; ++ks)
      offB[j][ks] = (wn * 64 + j * 32 + (lane & 31)) * B_STRIDE + (ks * 2 + (lane >> 5)) * 16;

  f32x16 acc[2][2];
#pragma unroll
  for (int i = 0; i < 2; ++i)
#pragma unroll
    for (int j = 0; j < 2; ++j) acc[i][j] = (f32x16)(0.f);

  const int NT = K_DIM / BK;   // 128

  // ---- prologue: decode tile 0 into buf0; preload A(tile0); prefetch words(tile1) ----
  {
    int2 w0 = gB[0];
    uint32_t o0[8], o1[8];
    unpack_word((uint32_t)w0.x, o0);
    unpack_word((uint32_t)w0.y, o1);
    *(uint4*)(BsB + dBoff[0]) = make_uint4(o0[0], o0[1], o0[2], o0[3]);
    *(uint4*)(BsB + dBoff[1]) = make_uint4(o0[4], o0[5], o0[6], o0[7]);
    *(uint4*)(BsB + dBoff[2]) = make_uint4(o1[0], o1[1], o1[2], o1[3]);
    *(uint4*)(BsB + dBoff[3]) = make_uint4(o1[4], o1[5], o1[6], o1[7]);
  }
  half8 aCur[2][4], aNxt[2][4];
#pragma unroll
  for (int i = 0; i < 2; ++i)
#pragma unroll
    for (int ks = 0; ks < 4; ++ks)
      aCur[i][ks] = *(const half8*)(pA[i] + ks * 1024);
#pragma unroll
  for (int i = 0; i < 2; ++i) pA[i] += KT_STRIDE;   // -> tile 1
  int2 wcur = gB[2];                                 // tile 1 words
  __syncthreads();

  for (int kt = 0; kt < NT; ++kt) {
    const int cur = kt & 1;

    // Prefetch: A(tile kt+1) into regs, words(tile kt+2). Pure register loads —
    // stay in flight across the barrier; consumed a full tile later.
#pragma unroll
    for (int i = 0; i < 2; ++i)
#pragma unroll
      for (int ks = 0; ks < 4; ++ks)
        aNxt[i][ks] = *(const half8*)(pA[i] + ks * 1024);
    if (kt < NT - 2) {
#pragma unroll
      for (int i = 0; i < 2; ++i) pA[i] += KT_STRIDE;
    }
    int kn2 = (kt + 2 < NT) ? (kt + 2) : (NT - 1);
    int2 wnxt = gB[kn2 * 2];

    // Compute tile kt from aCur + B buf[cur]
    const char* bb = BsB + cur * B_BUF;
#pragma unroll
    for (int ks = 0; ks < 4; ++ks) {
      half8 bf0 = *(const half8*)(bb + offB[0][ks]);
      half8 bf1 = *(const half8*)(bb + offB[1][ks]);
      acc[0][0] = __builtin_amdgcn_mfma_f32_32x32x16_f16(aCur[0][ks], bf0, acc[0][0], 0, 0, 0);
      acc[0][1] = __builtin_amdgcn_mfma_f32_32x32x16_f16(aCur[0][ks], bf1, acc[0][1], 0, 0, 0);
      acc[1][0] = __builtin_amdgcn_mfma_f32_32x32x16_f16(aCur[1][ks], bf0, acc[1][0], 0, 0, 0);
      acc[1][1] = __builtin_amdgcn_mfma_f32_32x32x16_f16(aCur[1][ks], bf1, acc[1][1], 0, 0, 0);
    }

    // Decode tile kt+1 (wcur) into the other buffer
    {
      char* wb = BsB + (cur ^ 1) * B_BUF;
      uint32_t o0[8], o1[8];
      unpack_word((uint32_t)wcur.x, o0);
      unpack_word((uint32_t)wcur.y, o1);
      *(uint4*)(wb + dBoff[0]) = make_uint4(o0[0], o0[1], o0[2], o0[3]);
      *(uint4*)(wb + dBoff[1]) = make_uint4(o0[4], o0[5], o0[6], o0[7]);
      *(uint4*)(wb + dBoff[2]) = make_uint4(o1[0], o1[1], o1[2], o1[3]);
      *(uint4*)(wb + dBoff[3]) = make_uint4(o1[4], o1[5], o1[6], o1[7]);
    }

    __syncthreads();   // single barrier per tile: writes(kt+1) visible; reads(kt) done
    wcur = wnxt;
#pragma unroll
    for (int i = 0; i < 2; ++i)
#pragma unroll
      for (int ks = 0; ks < 4; ++ks) aCur[i][ks] = aNxt[i][ks];
  }

  // Epilogue: 32x32 C/D (m74/m101): col(n)=lane&31, row(m)=(reg&3)+8*(reg>>2)+4*(lane>>5)
  // fp16 rounding replicated exactly: f16(y) + f16(bias) in half, widen to f32.
#pragma unroll
  for (int j = 0; j < 2; ++j) {
    int n = bn + wn * 64 + j * 32 + (lane & 31);
    __half hb = __float2half_rn(bias[n]);
#pragma unroll
    for (int i = 0; i < 2; ++i) {
      int mbase = bm + wm * 64 + i * 32 + 4 * (lane >> 5);
#pragma unroll
      for (int reg = 0; reg < 16; ++reg) {
        int m = mbase + (reg & 3) + 8 * (reg >> 2);
        __half hy = __float2half_rn(acc[i][j][reg]);
        out[(size_t)m * N_DIM + n] = __half2float(__hadd(hy, hb));
      }
    }
  }
}

// ================= fallback (R4 kernel, known-good): used only if ws too small =================
__device__ __forceinline__ uint32_t unpack_pair16(uint32_t u, int p) {
  uint32_t c0 = (u >> (4 * p)) & 3u;
  uint32_t c1 = (u >> (4 * p + 2)) & 3u;
  uint32_t lo = (c0 & 1u) * 0x3C00u + (c0 >> 1) * 0x0600u;
  uint32_t hi = (c1 & 1u) * 0x3C00u + (c1 >> 1) * 0x0600u;
  return lo | (hi << 16);
}

__global__ __launch_bounds__(NTHREADS, 2)
void ternary_gemm(const float* __restrict__ x,
                  const int*   __restrict__ pw,
                  const float* __restrict__ bias,
                  float*       __restrict__ out) {
  __shared__ __align__(16) char AsB[128 * B_STRIDE];
  __shared__ __align__(16) char BsB[128 * B_STRIDE];

  const int tid  = threadIdx.x;
  const int lane = tid & 63;
  const int w    = tid >> 6;
  const int wm   = w >> 1, wn = w & 1;
  const int bid  = blockIdx.x;
  const int bm   = (bid & 7) * 128;
  const int bn   = (bid >> 3) * 128;

  const int rT = tid >> 1, hT = tid & 1;
  const float* gA = x + (size_t)(bm + rT) * K_DIM + hT * 32;
  char* const  lA = AsB + rT * B_STRIDE + hT * 64;
  const int2* gB = (const int2*)pw + (size_t)(bn + rT) * (KP / 2) + hT;
  char* dBp[4];
#pragma unroll
  for (int h = 0; h < 4; ++h)
    dBp[h] = BsB + rT * B_STRIDE + (hT * 4 + h) * 16;

  int offA[4][2], offB[4][2];
#pragma unroll
  for (int i = 0; i < 4; ++i)
#pragma unroll
    for (int ks = 0; ks < 2; ++ks) {
      int c = ks * 4 + (lane >> 4);
      offA[i][ks] = (wm * 64 + i * 16 + (lane & 15)) * B_STRIDE + c * 16;
      offB[i][ks] = (wn * 64 + i * 16 + (lane & 15)) * B_STRIDE + c * 16;
    }

  f32x4 acc[4][4];
#pragma unroll
  for (int i = 0; i < 4; ++i)
#pragma unroll
    for (int j = 0; j < 4; ++j)
      acc[i][j] = (f32x4){0.f, 0.f, 0.f, 0.f};

  const int NT = K_DIM / BK;
  for (int kt = 0; kt < NT; ++kt) {
    __syncthreads();
    int2 wcur = gB[kt * 2];
    float4 av[8];
#pragma unroll
    for (int v = 0; v < 8; ++v) av[v] = *(const float4*)(gA + kt * BK + v * 4);
    uint32_t d0[8], d1[8];
#pragma unroll
    for (int p = 0; p < 8; ++p) d0[p] = unpack_pair16((uint32_t)wcur.x, p);
#pragma unroll
    for (int p = 0; p < 8; ++p) d1[p] = unpack_pair16((uint32_t)wcur.y, p);
    *(uint4*)dBp[0] = make_uint4(d0[0], d0[1], d0[2], d0[3]);
    *(uint4*)dBp[1] = make_uint4(d0[4], d0[5], d0[6], d0[7]);
    *(uint4*)dBp[2] = make_uint4(d1[0], d1[1], d1[2], d1[3]);
    *(uint4*)dBp[3] = make_uint4(d1[4], d1[5], d1[6], d1[7]);
#pragma unroll
    for (int v = 0; v < 4; ++v) {
      uint4 aw;
      aw.x = cvt2(av[2 * v].x, av[2 * v].y);
      aw.y = cvt2(av[2 * v].z, av[2 * v].w);
      aw.z = cvt2(av[2 * v + 1].x, av[2 * v + 1].y);
      aw.w = cvt2(av[2 * v + 1].z, av[2 * v + 1].w);
      *(uint4*)(lA + v * 16) = aw;
    }
    __syncthreads();
#pragma unroll
    for (int ks = 0; ks < 2; ++ks) {
      half8 af[4], bf[4];
#pragma unroll
      for (int i = 0; i < 4; ++i) af[i] = *(const half8*)(AsB + offA[i][ks]);
#pragma unroll
      for (int j = 0; j < 4; ++j) bf[j] = *(const half8*)(BsB + offB[j][ks]);
#pragma unroll
      for (int i = 0; i < 4; ++i)
#pragma unroll
        for (int j = 0; j < 4; ++j)
          acc[i][j] = __builtin_amdgcn_mfma_f32_16x16x32_f16(af[i], bf[j], acc[i][j], 0, 0, 0);
    }
  }
#pragma unroll
  for (int j = 0; j < 4; ++j) {
    int n = bn + wn * 64 + j * 16 + (lane & 15);
    __half hb = __float2half_rn(bias[n]);
#pragma unroll
    for (int i = 0; i < 4; ++i) {
      int m0 = bm + wm * 64 + i * 16 + (lane >> 4) * 4;
#pragma unroll
      for (int r = 0; r < 4; ++r) {
        __half hy = __float2half_rn(acc[i][j][r]);
        out[(size_t)(m0 + r) * N_DIM + n] = __half2float(__hadd(hy, hb));
      }
    }
  }
}

extern "C" void kernel_launch(void* const* d_in, const int* in_sizes, int n_in,
                              void* d_out, int out_size, void* d_ws, size_t ws_size,
                              hipStream_t stream) {
  (void)in_sizes; (void)n_in; (void)out_size;
  const float* x    = (const float*)d_in[0];
  const int*   pwp  = (const int*)d_in[1];
  const float* bias = (const float*)d_in[2];
  float*       outp = (float*)d_out;

  const size_t need = (size_t)M_DIM * K_DIM * 2;   // 16 MiB fp16 x (transposed)
  if (ws_size >= need) {
    char* xhT = (char*)d_ws;
    cvt_x_t<<<8 * 128, 256, 0, stream>>>(x, xhT);
    dim3 grid((M_DIM / BM) * (N_DIM / BN));        // 512 blocks
    ternary_gemm_rA<<<grid, NTHREADS, 0, stream>>>(xhT, pwp, bias, outp);
  } else {
    dim3 grid((M_DIM / 128) * (N_DIM / 128));      // 512 blocks
    ternary_gemm<<<grid, NTHREADS, 0, stream>>>(x, pwp, bias, outp);
  }
}

// Round 9
// 237.018 us; speedup vs baseline: 1.0995x; 1.0094x over previous
//
#include <hip/hip_runtime.h>
#include <hip/hip_fp16.h>
#include <stdint.h>

// Problem dims (fixed by reference)
// Reference dtypes: x fp16, bias fp16, out fp16 -> harness passes/reads FLOAT32.
// packed_w int32 (8192 x 512), 16 two-bit codes per word, values {0,1,3}.
#define M_DIM 1024
#define N_DIM 8192
#define K_DIM 8192
#define KP    (K_DIM / 16)   // 512 packed int32 words per weight row

#define BM 128
#define BN 128
#define BK 64
#define NTHREADS 256
#define B_STRIDE 144          // fallback kernel only

// Transposed A workspace layout (bytes), built by cvt_x_t:
//   mt(8):2 MiB | kt(128):16 KiB | i32(4):4 KiB | ks(4):1 KiB | q(2):512 | r(32):16
// A-fragment (i32, ks) = contiguous 1 KB at base + lane*16 (lane = q*32+r).
#define MT_STRIDE 2097152
#define KT_STRIDE 16384

typedef _Float16 half8   __attribute__((ext_vector_type(8)));
typedef __fp16   fp16x2  __attribute__((ext_vector_type(2)));
typedef float    f32x4   __attribute__((ext_vector_type(4)));
typedef float    f32x16  __attribute__((ext_vector_type(16)));

__device__ __forceinline__ uint32_t cvt2(float a, float b) {
  fp16x2 p = __builtin_amdgcn_cvt_pkrtz(a, b);   // RTZ exact: values are fp16-representable
  return __builtin_bit_cast(uint32_t, p);
}

// ---- consumer-side half-word ternary decode ----
// word = 16 codes; quad half (sh = quad*16) = 8 codes -> half8 MFMA B-fragment.
// h bytes [h1,h0]; U0 = h&0x3333 -> bytes [c4|c6<<4, c0|c2<<4]; U1<<16 = [c5|c7<<4, c1|c3<<4]<<16.
// W = U0 | (h<<14 & 0x33330000) -> bytes [c5|c7<<4, c4|c6<<4, c1|c3<<4, c0|c2<<4].
// comb0 = W.b0 | W.b2<<8 -> spread -> sel [c0,c1,c2,c3]; comb1 = W.b1 | W.b3<<8 -> [c4..c7].
// T byte-table [0x00,0x3C,0x06,0x42] = fp16 hi-bytes of {0,1,2,3} (low byte always 0).
__device__ __forceinline__ half8 dec_frag(uint32_t word, uint32_t sh) {
  const uint32_t T = 0x42063C00u;
  uint32_t h  = (word >> sh) & 0xFFFFu;
  uint32_t W  = (h & 0x3333u) | ((h << 14) & 0x33330000u);
  uint32_t c0 = __builtin_amdgcn_perm(0u, W, 0x04040200u);  // W.b0 | W.b2<<8
  uint32_t c1 = __builtin_amdgcn_perm(0u, W, 0x04040301u);  // W.b1 | W.b3<<8
  uint32_t s0 = (c0 * 0x1001u) & 0x03030303u;               // [c0,c1,c2,c3]
  uint32_t s1 = (c1 * 0x1001u) & 0x03030303u;               // [c4,c5,c6,c7]
  uint32_t P0 = __builtin_amdgcn_perm(0u, T, s0);
  uint32_t P1 = __builtin_amdgcn_perm(0u, T, s1);
  uint4 v;
  v.x = __builtin_amdgcn_perm(P0, 0u, 0x05000400u);  // fp16(c0), fp16(c1)
  v.y = __builtin_amdgcn_perm(P0, 0u, 0x07000600u);  // fp16(c2), fp16(c3)
  v.z = __builtin_amdgcn_perm(P1, 0u, 0x05000400u);  // fp16(c4), fp16(c5)
  v.w = __builtin_amdgcn_perm(P1, 0u, 0x07000600u);  // fp16(c6), fp16(c7)
  return __builtin_bit_cast(half8, v);
}

// ---- pre-pass: x f32 -> fp16, transposed-tiled into workspace (R8, verified) ----
__global__ __launch_bounds__(256)
void cvt_x_t(const float* __restrict__ x, char* __restrict__ xhT) {
  __shared__ __align__(16) char st[16384];
  const int b  = blockIdx.x;
  const int mt = b >> 7, kt = b & 127;
  const int t  = threadIdx.x;
#pragma unroll
  for (int p = 0; p < 8; ++p) {
    int f   = t + 256 * p;
    int R   = f >> 4;
    int cc4 = f & 15;
    float4 v = *(const float4*)(x + (size_t)(mt * 128 + R) * K_DIM + kt * 64 + cc4 * 4);
    uint32_t w0 = cvt2(v.x, v.y), w1 = cvt2(v.z, v.w);
    int c8 = cc4 >> 1, hh = cc4 & 1;
    int i32 = R >> 5, r = R & 31, ks = c8 >> 1, q = c8 & 1;
    *(uint2*)(st + i32 * 4096 + ks * 1024 + q * 512 + r * 16 + hh * 8) = make_uint2(w0, w1);
  }
  __syncthreads();
  char* outb = xhT + (size_t)mt * MT_STRIDE + (size_t)kt * KT_STRIDE;
#pragma unroll
  for (int e = 0; e < 4; ++e) {
    int d = (e * 256 + t) * 16;
    *(uint4*)(outb + d) = *(const uint4*)(st + d);
  }
}

// ====== fast path: A in regs, B raw-word LDS stage (2 KB dbuf) + decode-at-consumer ======
__global__ __launch_bounds__(NTHREADS, 2)
void ternary_gemm_dc(const char* __restrict__ xhT,
                     const int*  __restrict__ pw,
                     const float* __restrict__ bias,
                     float*       __restrict__ out) {
  __shared__ __align__(16) char stg[2 * 2048];   // raw packed words: 128 rows x int4, dbuf

  const int tid  = threadIdx.x;
  const int lane = tid & 63;
  const int w    = tid >> 6;
  const int wm   = w >> 1, wn = w & 1;
  const int bid  = blockIdx.x;
  const int mt   = bid & 7;           // XCD swizzle: one 2 MiB A-slab per XCD hot in L2
  const int bm   = mt * BM;
  const int bn   = (bid >> 3) * BN;

  // A register-load pointers (transposed ws): i -> i32 = wm*2+i; fragment ks at +ks*1024
  const char* pA[2];
#pragma unroll
  for (int i = 0; i < 2; ++i)
    pA[i] = xhT + (size_t)mt * MT_STRIDE + (wm * 2 + i) * 4096 + lane * 16;

  // Word staging: thread t -> row t>>1, word-pair t&1 (int2, coalesced global load)
  const int rT = tid >> 1, hT = tid & 1;
  const int2* gB = (const int2*)pw + (size_t)(bn + rT) * (KP / 2) + hT;
  const int stOff = rT * 16 + hT * 8;

  // Consumer rows: fragment j needs words of W-row wn*64 + j*32 + (lane&31)
  int rowOff[2];
#pragma unroll
  for (int j = 0; j < 2; ++j)
    rowOff[j] = (wn * 64 + j * 32 + (lane & 31)) * 16;
  const uint32_t sh = (lane >> 5) * 16;   // quad selects codes 0-7 vs 8-15 of each word

  f32x16 acc[2][2];
#pragma unroll
  for (int i = 0; i < 2; ++i)
#pragma unroll
    for (int j = 0; j < 2; ++j) acc[i][j] = (f32x16)(0.f);

  const int NT = K_DIM / BK;   // 128

  // ---- prologue: words(tile0)->stg[0]; A(tile0)->regs; words(tile1)->regs ----
  *(int2*)(stg + stOff) = gB[0];
  half8 aA[2][4], aB[2][4];
#pragma unroll
  for (int i = 0; i < 2; ++i)
#pragma unroll
    for (int ks = 0; ks < 4; ++ks)
      aA[i][ks] = *(const half8*)(pA[i] + ks * 1024);
#pragma unroll
  for (int i = 0; i < 2; ++i) pA[i] += KT_STRIDE;   // -> tile 1
  int2 wcur = gB[2];                                 // tile 1 words
  __syncthreads();

  auto step = [&](half8 (&aC)[2][4], half8 (&aN)[2][4], int cur, int kt) {
    // Prefetch A(kt+1) into the other register set (consumed next step)
#pragma unroll
    for (int i = 0; i < 2; ++i)
#pragma unroll
      for (int ks = 0; ks < 4; ++ks)
        aN[i][ks] = *(const half8*)(pA[i] + ks * 1024);
    if (kt < NT - 2) {
#pragma unroll
      for (int i = 0; i < 2; ++i) pA[i] += KT_STRIDE;
    }
    int kn2 = (kt + 2 < NT) ? (kt + 2) : (NT - 1);
    int2 wnxt = gB[kn2 * 2];

    // Read this tile's raw words (2 rows x int4); write next tile's words to other buffer
    uint32_t wr0[4], wr1[4];
    *(uint4*)wr0 = *(const uint4*)(stg + cur * 2048 + rowOff[0]);
    *(uint4*)wr1 = *(const uint4*)(stg + cur * 2048 + rowOff[1]);
    *(int2*)(stg + (cur ^ 1) * 2048 + stOff) = wcur;

    // Compute: decode fragments in-register, adjacent to MFMAs
#pragma unroll
    for (int ks = 0; ks < 4; ++ks) {
      half8 bf0 = dec_frag(wr0[ks], sh);
      half8 bf1 = dec_frag(wr1[ks], sh);
      acc[0][0] = __builtin_amdgcn_mfma_f32_32x32x16_f16(aC[0][ks], bf0, acc[0][0], 0, 0, 0);
      acc[0][1] = __builtin_amdgcn_mfma_f32_32x32x16_f16(aC[0][ks], bf1, acc[0][1], 0, 0, 0);
      acc[1][0] = __builtin_amdgcn_mfma_f32_32x32x16_f16(aC[1][ks], bf0, acc[1][0], 0, 0, 0);
      acc[1][1] = __builtin_amdgcn_mfma_f32_32x32x16_f16(aC[1][ks], bf1, acc[1][1], 0, 0, 0);
    }

    __syncthreads();   // single barrier: word-writes(kt+1) visible; word-reads(kt) done
    wcur = wnxt;
  };

  for (int kt = 0; kt < NT; kt += 2) {   // 2x unrolled: A-register ping-pong without copies
    step(aA, aB, 0, kt);
    step(aB, aA, 1, kt + 1);
  }

  // Epilogue: 32x32 C/D (m74/m101): col(n)=lane&31, row(m)=(reg&3)+8*(reg>>2)+4*(lane>>5)
  // fp16 rounding replicated exactly: f16(y) + f16(bias) in half, widen to f32.
#pragma unroll
  for (int j = 0; j < 2; ++j) {
    int n = bn + wn * 64 + j * 32 + (lane & 31);
    __half hb = __float2half_rn(bias[n]);
#pragma unroll
    for (int i = 0; i < 2; ++i) {
      int mbase = bm + wm * 64 + i * 32 + 4 * (lane >> 5);
#pragma unroll
      for (int reg = 0; reg < 16; ++reg) {
        int m = mbase + (reg & 3) + 8 * (reg >> 2);
        __half hy = __float2half_rn(acc[i][j][reg]);
        out[(size_t)m * N_DIM + n] = __half2float(__hadd(hy, hb));
      }
    }
  }
}

// ================= fallback (R4 kernel, known-good): used only if ws too small =================
__device__ __forceinline__ uint32_t unpack_pair16(uint32_t u, int p) {
  uint32_t c0 = (u >> (4 * p)) & 3u;
  uint32_t c1 = (u >> (4 * p + 2)) & 3u;
  uint32_t lo = (c0 & 1u) * 0x3C00u + (c0 >> 1) * 0x0600u;
  uint32_t hi = (c1 & 1u) * 0x3C00u + (c1 >> 1) * 0x0600u;
  return lo | (hi << 16);
}

__global__ __launch_bounds__(NTHREADS, 2)
void ternary_gemm(const float* __restrict__ x,
                  const int*   __restrict__ pw,
                  const float* __restrict__ bias,
                  float*       __restrict__ out) {
  __shared__ __align__(16) char AsB[128 * B_STRIDE];
  __shared__ __align__(16) char BsB[128 * B_STRIDE];

  const int tid  = threadIdx.x;
  const int lane = tid & 63;
  const int w    = tid >> 6;
  const int wm   = w >> 1, wn = w & 1;
  const int bid  = blockIdx.x;
  const int bm   = (bid & 7) * 128;
  const int bn   = (bid >> 3) * 128;

  const int rT = tid >> 1, hT = tid & 1;
  const float* gA = x + (size_t)(bm + rT) * K_DIM + hT * 32;
  char* const  lA = AsB + rT * B_STRIDE + hT * 64;
  const int2* gB = (const int2*)pw + (size_t)(bn + rT) * (KP / 2) + hT;
  char* dBp[4];
#pragma unroll
  for (int h = 0; h < 4; ++h)
    dBp[h] = BsB + rT * B_STRIDE + (hT * 4 + h) * 16;

  int offA[4][2], offB[4][2];
#pragma unroll
  for (int i = 0; i < 4; ++i)
#pragma unroll
    for (int ks = 0; ks < 2; ++ks) {
      int c = ks * 4 + (lane >> 4);
      offA[i][ks] = (wm * 64 + i * 16 + (lane & 15)) * B_STRIDE + c * 16;
      offB[i][ks] = (wn * 64 + i * 16 + (lane & 15)) * B_STRIDE + c * 16;
    }

  f32x4 acc[4][4];
#pragma unroll
  for (int i = 0; i < 4; ++i)
#pragma unroll
    for (int j = 0; j < 4; ++j)
      acc[i][j] = (f32x4){0.f, 0.f, 0.f, 0.f};

  const int NT = K_DIM / BK;
  for (int kt = 0; kt < NT; ++kt) {
    __syncthreads();
    int2 wcur = gB[kt * 2];
    float4 av[8];
#pragma unroll
    for (int v = 0; v < 8; ++v) av[v] = *(const float4*)(gA + kt * BK + v * 4);
    uint32_t d0[8], d1[8];
#pragma unroll
    for (int p = 0; p < 8; ++p) d0[p] = unpack_pair16((uint32_t)wcur.x, p);
#pragma unroll
    for (int p = 0; p < 8; ++p) d1[p] = unpack_pair16((uint32_t)wcur.y, p);
    *(uint4*)dBp[0] = make_uint4(d0[0], d0[1], d0[2], d0[3]);
    *(uint4*)dBp[1] = make_uint4(d0[4], d0[5], d0[6], d0[7]);
    *(uint4*)dBp[2] = make_uint4(d1[0], d1[1], d1[2], d1[3]);
    *(uint4*)dBp[3] = make_uint4(d1[4], d1[5], d1[6], d1[7]);
#pragma unroll
    for (int v = 0; v < 4; ++v) {
      uint4 aw;
      aw.x = cvt2(av[2 * v].x, av[2 * v].y);
      aw.y = cvt2(av[2 * v].z, av[2 * v].w);
      aw.z = cvt2(av[2 * v + 1].x, av[2 * v + 1].y);
      aw.w = cvt2(av[2 * v + 1].z, av[2 * v + 1].w);
      *(uint4*)(lA + v * 16) = aw;
    }
    __syncthreads();
#pragma unroll
    for (int ks = 0; ks < 2; ++ks) {
      half8 af[4], bf[4];
#pragma unroll
      for (int i = 0; i < 4; ++i) af[i] = *(const half8*)(AsB + offA[i][ks]);
#pragma unroll
      for (int j = 0; j < 4; ++j) bf[j] = *(const half8*)(BsB + offB[j][ks]);
#pragma unroll
      for (int i = 0; i < 4; ++i)
#pragma unroll
        for (int j = 0; j < 4; ++j)
          acc[i][j] = __builtin_amdgcn_mfma_f32_16x16x32_f16(af[i], bf[j], acc[i][j], 0, 0, 0);
    }
  }
#pragma unroll
  for (int j = 0; j < 4; ++j) {
    int n = bn + wn * 64 + j * 16 + (lane & 15);
    __half hb = __float2half_rn(bias[n]);
#pragma unroll
    for (int i = 0; i < 4; ++i) {
      int m0 = bm + wm * 64 + i * 16 + (lane >> 4) * 4;
#pragma unroll
      for (int r = 0; r < 4; ++r) {
        __half hy = __float2half_rn(acc[i][j][r]);
        out[(size_t)(m0 + r) * N_DIM + n] = __half2float(__hadd(hy, hb));
      }
    }
  }
}

extern "C" void kernel_launch(void* const* d_in, const int* in_sizes, int n_in,
                              void* d_out, int out_size, void* d_ws, size_t ws_size,
                              hipStream_t stream) {
  (void)in_sizes; (void)n_in; (void)out_size;
  const float* x    = (const float*)d_in[0];
  const int*   pwp  = (const int*)d_in[1];
  const float* bias = (const float*)d_in[2];
  float*       outp = (float*)d_out;

  const size_t need = (size_t)M_DIM * K_DIM * 2;   // 16 MiB fp16 x (transposed)
  if (ws_size >= need) {
    char* xhT = (char*)d_ws;
    cvt_x_t<<<8 * 128, 256, 0, stream>>>(x, xhT);
    dim3 grid((M_DIM / BM) * (N_DIM / BN));        // 512 blocks
    ternary_gemm_dc<<<grid, NTHREADS, 0, stream>>>(xhT, pwp, bias, outp);
  } else {
    dim3 grid((M_DIM / 128) * (N_DIM / 128));      // 512 blocks
    ternary_gemm<<<grid, NTHREADS, 0, stream>>>(x, pwp, bias, outp);
  }
}